// Round 5
// baseline (2141.602 us; speedup 1.0000x reference)
//
#include <hip/hip_runtime.h>
#include <math.h>

// M3GNet-like GNN forward. N=10000 nodes, E=160000 edges, T=1200000 triplets,
// D=256, DM=64, H=1024, L=3, output = scalar mean energy (fp32).
//
// R4: split k_triplet (240us/layer, serialized per-triplet swizzle-reduce +
// online-softmax chain) into:
//   k_logit  - thread per triplet, Chebyshev recurrence for cos(k*theta),
//              register dot product, no cross-lane ops.
//   k_attend - wave per edge, one reduce per edge, independent FMA loop.
// k_scatter now stores cos(angle) + edge id (no acos needed).

#define DM 64
#define DMODEL 256
#define HDIM 1024

__global__ void k_embed(const int* __restrict__ an, const float* __restrict__ emb,
                        float* __restrict__ x) {
    int n = blockIdx.x;
    int d = threadIdx.x;          // blockDim = 256
    x[n * DMODEL + d] = emb[an[n] * DMODEL + d];
}

__global__ void k_edge_geom(const float* __restrict__ r, float* __restrict__ bl,
                            float* __restrict__ rn, int E) {
    int e = blockIdx.x * blockDim.x + threadIdx.x;
    if (e >= E) return;
    float a = r[e * 3 + 0], b = r[e * 3 + 1], c = r[e * 3 + 2];
    float l = sqrtf(a * a + b * b + c * c);
    bl[e] = l;
    float inv = 1.0f / l;
    // note: reference uses -r/|r| for both operands of the dot; signs cancel.
    rn[e * 3 + 0] = a * inv;
    rn[e * 3 + 1] = b * inv;
    rn[e * 3 + 2] = c * inv;
}

__global__ void k_hist(const int* __restrict__ td, int* __restrict__ cnt, int T) {
    int t = blockIdx.x * blockDim.x + threadIdx.x;
    if (t < T) atomicAdd(&cnt[td[t]], 1);
}

// ---- 3-phase exclusive scan of cnt[E] -> rowp[E+1] ----
__global__ __launch_bounds__(256) void k_scan_part(
    const int* __restrict__ cnt, int* __restrict__ bsum, int E) {
    __shared__ int sm[4];
    int tid = threadIdx.x;
    int i = blockIdx.x * 256 + tid;
    int v = (i < E) ? cnt[i] : 0;
    for (int off = 32; off > 0; off >>= 1) v += __shfl_xor(v, off, 64);
    if ((tid & 63) == 0) sm[tid >> 6] = v;
    __syncthreads();
    if (tid == 0) bsum[blockIdx.x] = sm[0] + sm[1] + sm[2] + sm[3];
}

// single block: in-place exclusive scan of bsum[nb] (nb <= 1024)
__global__ __launch_bounds__(1024) void k_scan_mid(int* __restrict__ bsum, int nb) {
    __shared__ int sm[1024];
    int tid = threadIdx.x;
    int v = (tid < nb) ? bsum[tid] : 0;
    sm[tid] = v;
    __syncthreads();
    for (int off = 1; off < 1024; off <<= 1) {
        int u = (tid >= off) ? sm[tid - off] : 0;
        __syncthreads();
        sm[tid] += u;
        __syncthreads();
    }
    if (tid < nb) bsum[tid] = sm[tid] - v;   // inclusive -> exclusive
}

__global__ __launch_bounds__(256) void k_scan_final(
    const int* __restrict__ cnt, const int* __restrict__ bsum,
    int* __restrict__ rowp, int E, int T) {
    __shared__ int sm[256];
    int tid = threadIdx.x;
    int i = blockIdx.x * 256 + tid;
    int v = (i < E) ? cnt[i] : 0;
    sm[tid] = v;
    __syncthreads();
    for (int off = 1; off < 256; off <<= 1) {
        int u = (tid >= off) ? sm[tid - off] : 0;
        __syncthreads();
        sm[tid] += u;
        __syncthreads();
    }
    if (i < E) rowp[i] = bsum[blockIdx.x] + sm[tid] - v;
    if (i == 0) rowp[E] = T;
}

// scatter triplets into segment order; store cos(angle) (Chebyshev arg) and
// the edge id per position; permute t_src.
__global__ void k_scatter(const int* __restrict__ ts, const int* __restrict__ td,
                          const int* __restrict__ rowp, int* __restrict__ cursor,
                          const float* __restrict__ rn,
                          int* __restrict__ srcs, float* __restrict__ cosv,
                          int* __restrict__ eids, int T) {
    int t = blockIdx.x * blockDim.x + threadIdx.x;
    if (t >= T) return;
    int a = ts[t], b = td[t];
    float d = rn[a * 3 + 0] * rn[b * 3 + 0]
            + rn[a * 3 + 1] * rn[b * 3 + 1]
            + rn[a * 3 + 2] * rn[b * 3 + 2];
    d = fminf(1.0f, fmaxf(-1.0f, d));
    int pos = rowp[b] + atomicAdd(&cursor[b], 1);
    srcs[pos] = a;
    cosv[pos] = d;
    eids[pos] = b;
}

// xs = x@Wsrc + bsrc ; xd = x@Wdst + bdst   (wave per node, lane = dm)
__global__ __launch_bounds__(256) void k_node_proj(
    const float* __restrict__ x,
    const float* __restrict__ Ws, const float* __restrict__ bs,
    const float* __restrict__ Wd, const float* __restrict__ bd,
    float* __restrict__ xs, float* __restrict__ xd, int N) {
    int lane = threadIdx.x & 63;
    int n = blockIdx.x * 4 + (threadIdx.x >> 6);
    if (n >= N) return;
    const float* xr = x + (size_t)n * DMODEL;
    float as = 0.f, ad = 0.f;
    for (int d = 0; d < DMODEL; ++d) {
        float xv = xr[d];
        as = fmaf(xv, Ws[d * DM + lane], as);
        ad = fmaf(xv, Wd[d * DM + lane], ad);
    }
    xs[n * DM + lane] = as + bs[lane];
    xd[n * DM + lane] = ad + bd[lane];
}

// xij[e][m] = RBF(bl[e]) @ Wedge + bedge + xs[g_src[e]] + xd[g_dst[e]]
// 64-edge x 64-dm tile per block; RBF A-tile computed on the fly into LDS.
__global__ __launch_bounds__(256) void k_xij(
    const float* __restrict__ bl,
    const float* __restrict__ We, const float* __restrict__ be,
    const float* __restrict__ xs, const float* __restrict__ xd,
    const int* __restrict__ gs, const int* __restrict__ gd,
    float* __restrict__ xij, int E) {
    __shared__ float A[64][65];
    __shared__ float W[64][65];
    int tid = threadIdx.x;
    int e0 = blockIdx.x * 64;
    int ty = tid >> 4, tx = tid & 15;
    const float step = 8.0f / 255.0f;
    const float gamma = (255.0f / 8.0f) * (255.0f / 8.0f);
    float acc[4][4] = {};
    for (int k0 = 0; k0 < DMODEL; k0 += 64) {
        for (int i = 0; i < 16; ++i) {
            int flat = i * 256 + tid;
            int row = flat >> 6;      // wave-uniform
            int col = flat & 63;      // = lane
            int ee = e0 + row;
            float blv = (ee < E) ? bl[ee] : 0.f;
            float c = (float)(k0 + col) * step;
            float dd = blv - c;
            A[row][col] = __expf(-gamma * dd * dd);
            W[row][col] = We[(k0 + row) * DM + col];
        }
        __syncthreads();
        for (int kk = 0; kk < 64; ++kk) {
            float av[4], wv[4];
            for (int i = 0; i < 4; ++i) av[i] = A[ty * 4 + i][kk];
            for (int j = 0; j < 4; ++j) wv[j] = W[kk][tx * 4 + j];
            for (int i = 0; i < 4; ++i)
                for (int j = 0; j < 4; ++j)
                    acc[i][j] = fmaf(av[i], wv[j], acc[i][j]);
        }
        __syncthreads();
    }
    for (int i = 0; i < 4; ++i) {
        int e = e0 + ty * 4 + i;
        if (e >= E) continue;
        int s = gs[e], d2 = gd[e];
        for (int j = 0; j < 4; ++j) {
            int m = tx * 4 + j;
            xij[e * DM + m] = acc[i][j] + xs[s * DM + m] + xd[d2 * DM + m] + be[m];
        }
    }
}

// thread per triplet: logit[p] = sum_k silu(T_k(cos) + xs_row[k] + xe_row[k]) * attn[k]
// Chebyshev recurrence T_k = 2c*T_{k-1} - T_{k-2}; float4 row loads; no
// cross-lane ops at all.
__global__ __launch_bounds__(256) void k_logit(
    const float* __restrict__ xij, const float* __restrict__ cosv,
    const int* __restrict__ srcs, const int* __restrict__ eids,
    const float* __restrict__ attn_l, float* __restrict__ logits, int T) {
    int p = blockIdx.x * 256 + threadIdx.x;
    if (p >= T) return;
    int s = srcs[p], e = eids[p];
    float c = cosv[p];
    float c2 = 2.0f * c;
    const float4* xsr = (const float4*)(xij + (size_t)s * DM);
    const float4* xer = (const float4*)(xij + (size_t)e * DM);
    float t0 = 1.0f, t1 = c;
    float acc = 0.f;
    #pragma unroll
    for (int j = 0; j < 16; ++j) {
        float4 a4 = xsr[j];
        float4 b4 = xer[j];
        float u[4] = {a4.x + b4.x, a4.y + b4.y, a4.z + b4.z, a4.w + b4.w};
        #pragma unroll
        for (int q = 0; q < 4; ++q) {
            int k = j * 4 + q;
            float tk;
            if (k == 0)      tk = 1.0f;
            else if (k == 1) tk = c;
            else { tk = fmaf(c2, t1, -t0); t0 = t1; t1 = tk; }
            float v = tk + u[q];
            float sl = v / (1.0f + __expf(-v));
            acc = fmaf(sl, attn_l[k], acc);
        }
    }
    logits[p] = acc;
}

// wave per edge: softmax over segment logits (one reduce per edge), then
// weighted gather-sum of source rows; one atomic per edge per lane.
__global__ __launch_bounds__(256) void k_attend(
    const float* __restrict__ xij, const float* __restrict__ logits,
    const int* __restrict__ srcs, const int* __restrict__ rowp,
    const int* __restrict__ gd, float* __restrict__ ft, int E, int nwaves) {
    int lane = threadIdx.x & 63;
    int wid = (blockIdx.x * blockDim.x + threadIdx.x) >> 6;
    for (int e = wid; e < E; e += nwaves) {
        int beg = rowp[e], end = rowp[e + 1];
        if (beg == end) continue;
        float lm = -1e30f;
        for (int p = beg + lane; p < end; p += 64) lm = fmaxf(lm, logits[p]);
        for (int off = 32; off > 0; off >>= 1)
            lm = fmaxf(lm, __shfl_xor(lm, off, 64));
        float ls = 0.f;
        for (int p = beg + lane; p < end; p += 64) ls += __expf(logits[p] - lm);
        for (int off = 32; off > 0; off >>= 1) ls += __shfl_xor(ls, off, 64);
        float inv = 1.0f / ls;
        float acc = 0.f;
        for (int p = beg; p < end; ++p) {
            float w = __expf(logits[p] - lm) * inv;
            acc = fmaf(w, xij[(size_t)srcs[p] * DM + lane], acc);
        }
        atomicAdd(&ft[gd[e] * DM + lane], acc);
    }
}

// h = silu(ft @ W1 + b1): 64-node x 64-hcol tile, 4x4 register blocking.
// grid (ceil(N/64), HDIM/64) = (157, 16)
__global__ __launch_bounds__(256) void k_ffn1(
    const float* __restrict__ ft, const float* __restrict__ W1,
    const float* __restrict__ b1, float* __restrict__ h, int N) {
    __shared__ float A[32][68];   // A[kk][node], k-major, +4 pad (16B-aligned rows)
    __shared__ float B[32][68];   // B[kk][col]
    int tid = threadIdx.x;
    int n0 = blockIdx.x * 64;
    int c0 = blockIdx.y * 64;
    int ty = tid >> 4, tx = tid & 15;
    float acc[4][4] = {};
    for (int k0 = 0; k0 < DM; k0 += 32) {
        for (int i = 0; i < 8; ++i) {
            int flat = i * 256 + tid;
            int row = flat >> 5, kk = flat & 31;
            int n = n0 + row;
            A[kk][row] = (n < N) ? ft[(size_t)n * DM + k0 + kk] : 0.f;
        }
        for (int i = 0; i < 8; ++i) {
            int flat = i * 256 + tid;
            int kk = flat >> 6, col = flat & 63;
            B[kk][col] = W1[(size_t)(k0 + kk) * HDIM + c0 + col];
        }
        __syncthreads();
        for (int kk = 0; kk < 32; ++kk) {
            float4 av = *(const float4*)&A[kk][ty * 4];
            float4 bv = *(const float4*)&B[kk][tx * 4];
            float a4[4] = {av.x, av.y, av.z, av.w};
            float b4[4] = {bv.x, bv.y, bv.z, bv.w};
            for (int i = 0; i < 4; ++i)
                for (int j = 0; j < 4; ++j)
                    acc[i][j] = fmaf(a4[i], b4[j], acc[i][j]);
        }
        __syncthreads();
    }
    float4 bb = *(const float4*)&b1[c0 + tx * 4];
    float b4[4] = {bb.x, bb.y, bb.z, bb.w};
    for (int i = 0; i < 4; ++i) {
        int n = n0 + ty * 4 + i;
        if (n >= N) continue;
        float4 o;
        float v0 = acc[i][0] + b4[0], v1 = acc[i][1] + b4[1];
        float v2 = acc[i][2] + b4[2], v3 = acc[i][3] + b4[3];
        o.x = v0 / (1.0f + __expf(-v0));
        o.y = v1 / (1.0f + __expf(-v1));
        o.z = v2 / (1.0f + __expf(-v2));
        o.w = v3 / (1.0f + __expf(-v3));
        *(float4*)&h[(size_t)n * HDIM + c0 + tx * 4] = o;
    }
}

// x = h @ W2 + b2: 64-node x 64-col tile, 4x4 register blocking.
// grid (ceil(N/64), DMODEL/64) = (157, 4)
__global__ __launch_bounds__(256) void k_ffn2(
    const float* __restrict__ h, const float* __restrict__ W2,
    const float* __restrict__ b2, float* __restrict__ x, int N) {
    __shared__ float A[32][68];
    __shared__ float B[32][68];
    int tid = threadIdx.x;
    int n0 = blockIdx.x * 64;
    int c0 = blockIdx.y * 64;
    int ty = tid >> 4, tx = tid & 15;
    float acc[4][4] = {};
    for (int k0 = 0; k0 < HDIM; k0 += 32) {
        for (int i = 0; i < 8; ++i) {
            int flat = i * 256 + tid;
            int row = flat >> 5, kk = flat & 31;
            int n = n0 + row;
            A[kk][row] = (n < N) ? h[(size_t)n * HDIM + k0 + kk] : 0.f;
        }
        for (int i = 0; i < 8; ++i) {
            int flat = i * 256 + tid;
            int kk = flat >> 6, col = flat & 63;
            B[kk][col] = W2[(size_t)(k0 + kk) * DMODEL + c0 + col];
        }
        __syncthreads();
        for (int kk = 0; kk < 32; ++kk) {
            float4 av = *(const float4*)&A[kk][ty * 4];
            float4 bv = *(const float4*)&B[kk][tx * 4];
            float a4[4] = {av.x, av.y, av.z, av.w};
            float b4[4] = {bv.x, bv.y, bv.z, bv.w};
            for (int i = 0; i < 4; ++i)
                for (int j = 0; j < 4; ++j)
                    acc[i][j] = fmaf(a4[i], b4[j], acc[i][j]);
        }
        __syncthreads();
    }
    float4 bb = *(const float4*)&b2[c0 + tx * 4];
    float b4[4] = {bb.x, bb.y, bb.z, bb.w};
    for (int i = 0; i < 4; ++i) {
        int n = n0 + ty * 4 + i;
        if (n >= N) continue;
        float4 o;
        o.x = acc[i][0] + b4[0];
        o.y = acc[i][1] + b4[1];
        o.z = acc[i][2] + b4[2];
        o.w = acc[i][3] + b4[3];
        *(float4*)&x[(size_t)n * DMODEL + c0 + tx * 4] = o;
    }
}

// grid-stride dot(x, tiled Wfc) with per-block LDS reduction -> 1 atomic/block.
__global__ __launch_bounds__(256) void k_out_reduce(
    const float* __restrict__ x, const float* __restrict__ Wfc,
    float* __restrict__ acc, int NT) {
    __shared__ float sm[4];
    int tid = threadIdx.x;
    float v = 0.f;
    for (int i = blockIdx.x * blockDim.x + tid; i < NT; i += gridDim.x * blockDim.x)
        v = fmaf(x[i], Wfc[i & (DMODEL - 1)], v);
    for (int off = 32; off > 0; off >>= 1) v += __shfl_xor(v, off, 64);
    if ((tid & 63) == 0) sm[tid >> 6] = v;
    __syncthreads();
    if (tid == 0) {
        float s = sm[0] + sm[1] + sm[2] + sm[3];
        atomicAdd(acc, s);
    }
}

__global__ void k_out_final(const float* __restrict__ acc, const float* __restrict__ bfc,
                            float* __restrict__ out, float invN) {
    out[0] = acc[0] * invN + bfc[0];
}

extern "C" void kernel_launch(void* const* d_in, const int* in_sizes, int n_in,
                              void* d_out, int out_size, void* d_ws, size_t ws_size,
                              hipStream_t stream) {
    const int*   an    = (const int*)d_in[0];
    const int*   gs    = (const int*)d_in[1];
    const int*   gd    = (const int*)d_in[2];
    const int*   ts    = (const int*)d_in[3];
    const int*   td    = (const int*)d_in[4];
    const float* r     = (const float*)d_in[5];
    const float* emb   = (const float*)d_in[6];
    const float* Wsrc  = (const float*)d_in[7];
    const float* bsrc  = (const float*)d_in[8];
    const float* Wdst  = (const float*)d_in[9];
    const float* bdst  = (const float*)d_in[10];
    const float* Wedge = (const float*)d_in[11];
    const float* bedge = (const float*)d_in[12];
    const float* attn  = (const float*)d_in[13];
    const float* W1    = (const float*)d_in[14];
    const float* b1    = (const float*)d_in[15];
    const float* W2    = (const float*)d_in[16];
    const float* b2    = (const float*)d_in[17];
    const float* Wfc   = (const float*)d_in[18];
    const float* bfc   = (const float*)d_in[19];

    const int N = in_sizes[0];
    const int E = in_sizes[1];
    const int T = in_sizes[3];

    char* w = (char*)d_ws;
    size_t off = 0;
    auto alloc = [&](size_t elems) {
        void* p = w + off;
        off += ((elems * 4 + 255) / 256) * 256;
        return p;
    };
    float* x      = (float*)alloc((size_t)N * DMODEL);
    float* rn     = (float*)alloc((size_t)E * 3);
    float* bl     = (float*)alloc((size_t)E);
    int*   cnt    = (int*)  alloc((size_t)E);
    int*   rowp   = (int*)  alloc((size_t)E + 1);
    int*   bsum   = (int*)  alloc(1024);
    int*   srcs   = (int*)  alloc((size_t)T);
    float* cosv   = (float*)alloc((size_t)T);
    int*   eids   = (int*)  alloc((size_t)T);
    float* logits = (float*)alloc((size_t)T);
    float* xs     = (float*)alloc((size_t)N * DM);
    float* xd     = (float*)alloc((size_t)N * DM);
    float* xij    = (float*)alloc((size_t)E * DM);
    float* ft     = (float*)alloc((size_t)N * DM);
    float* h      = (float*)alloc((size_t)N * HDIM);
    float* accs   = (float*)alloc(16);
    (void)ws_size; (void)n_in; (void)out_size;

    const int nbScan = (E + 255) / 256;   // 625 <= 1024

    // ---- setup (layer-invariant) ----
    k_embed<<<N, 256, 0, stream>>>(an, emb, x);
    k_edge_geom<<<(E + 255) / 256, 256, 0, stream>>>(r, bl, rn, E);
    hipMemsetAsync(cnt, 0, (size_t)E * 4, stream);
    k_hist<<<(T + 255) / 256, 256, 0, stream>>>(td, cnt, T);
    k_scan_part<<<nbScan, 256, 0, stream>>>(cnt, bsum, E);
    k_scan_mid<<<1, 1024, 0, stream>>>(bsum, nbScan);
    k_scan_final<<<nbScan, 256, 0, stream>>>(cnt, bsum, rowp, E, T);
    hipMemsetAsync(cnt, 0, (size_t)E * 4, stream);
    k_scatter<<<(T + 255) / 256, 256, 0, stream>>>(ts, td, rowp, cnt, rn,
                                                   srcs, cosv, eids, T);

    // ---- layers ----
    for (int l = 0; l < 3; ++l) {
        k_node_proj<<<(N + 3) / 4, 256, 0, stream>>>(
            x, Wsrc + l * DMODEL * DM, bsrc + l * DM,
            Wdst + l * DMODEL * DM, bdst + l * DM, xs, xd, N);
        k_xij<<<(E + 63) / 64, 256, 0, stream>>>(
            bl, Wedge + l * DMODEL * DM, bedge + l * DM, xs, xd, gs, gd, xij, E);
        k_logit<<<(T + 255) / 256, 256, 0, stream>>>(
            xij, cosv, srcs, eids, attn + l * DM, logits, T);
        hipMemsetAsync(ft, 0, (size_t)N * DM * 4, stream);
        k_attend<<<2500, 256, 0, stream>>>(
            xij, logits, srcs, rowp, gd, ft, E, 2500 * 4);
        k_ffn1<<<dim3((N + 63) / 64, HDIM / 64), 256, 0, stream>>>(
            ft, W1 + l * DM * HDIM, b1 + l * HDIM, h, N);
        k_ffn2<<<dim3((N + 63) / 64, DMODEL / 64), 256, 0, stream>>>(
            h, W2 + l * HDIM * DMODEL, b2 + l * DMODEL, x, N);
    }

    // ---- output head ----
    hipMemsetAsync(accs, 0, 4, stream);
    k_out_reduce<<<120, 256, 0, stream>>>(x, Wfc, accs, N * DMODEL);
    k_out_final<<<1, 1, 0, stream>>>(accs, bfc, (float*)d_out, 1.0f / (float)N);
}

// Round 6
// 1626.423 us; speedup vs baseline: 1.3168x; 1.3168x over previous
//
#include <hip/hip_runtime.h>
#include <math.h>

// M3GNet-like GNN forward. N=10000 nodes, E=160000 edges, T=1200000 triplets,
// D=256, DM=64, H=1024, L=3, output = scalar mean energy (fp32).
//
// R5:
//  - k_attend: thread per (edge, channel-quad), no cross-lane ops, no atomics;
//    writes msg[E][64] (aliases h buffer - disjoint lifetimes).
//  - k_aggregate: edge-CSR by gd (built once in setup) reduces msg -> ft.
//    Removes all 10.2M atomics/layer + the ft memset.
//  - k_xij: ffn-style k-major LDS (A[32][68]/B[32][68], 16B-aligned rows,
//    float4 ds reads). Old [64][65] layout caused 1.5e7 bank conflicts
//    (compiler-merged misaligned b128) and 8 scalar ds_reads per 16 FMA.

#define DM 64
#define DMODEL 256
#define HDIM 1024

__global__ void k_embed(const int* __restrict__ an, const float* __restrict__ emb,
                        float* __restrict__ x) {
    int n = blockIdx.x;
    int d = threadIdx.x;          // blockDim = 256
    x[n * DMODEL + d] = emb[an[n] * DMODEL + d];
}

__global__ void k_edge_geom(const float* __restrict__ r, float* __restrict__ bl,
                            float* __restrict__ rn, int E) {
    int e = blockIdx.x * blockDim.x + threadIdx.x;
    if (e >= E) return;
    float a = r[e * 3 + 0], b = r[e * 3 + 1], c = r[e * 3 + 2];
    float l = sqrtf(a * a + b * b + c * c);
    bl[e] = l;
    float inv = 1.0f / l;
    // note: reference uses -r/|r| for both operands of the dot; signs cancel.
    rn[e * 3 + 0] = a * inv;
    rn[e * 3 + 1] = b * inv;
    rn[e * 3 + 2] = c * inv;
}

__global__ void k_hist(const int* __restrict__ idx, int* __restrict__ cnt, int M) {
    int t = blockIdx.x * blockDim.x + threadIdx.x;
    if (t < M) atomicAdd(&cnt[idx[t]], 1);
}

// ---- 3-phase exclusive scan of cnt[M] -> rowp[M+1] (generic) ----
__global__ __launch_bounds__(256) void k_scan_part(
    const int* __restrict__ cnt, int* __restrict__ bsum, int M) {
    __shared__ int sm[4];
    int tid = threadIdx.x;
    int i = blockIdx.x * 256 + tid;
    int v = (i < M) ? cnt[i] : 0;
    for (int off = 32; off > 0; off >>= 1) v += __shfl_xor(v, off, 64);
    if ((tid & 63) == 0) sm[tid >> 6] = v;
    __syncthreads();
    if (tid == 0) bsum[blockIdx.x] = sm[0] + sm[1] + sm[2] + sm[3];
}

__global__ __launch_bounds__(1024) void k_scan_mid(int* __restrict__ bsum, int nb) {
    __shared__ int sm[1024];
    int tid = threadIdx.x;
    int v = (tid < nb) ? bsum[tid] : 0;
    sm[tid] = v;
    __syncthreads();
    for (int off = 1; off < 1024; off <<= 1) {
        int u = (tid >= off) ? sm[tid - off] : 0;
        __syncthreads();
        sm[tid] += u;
        __syncthreads();
    }
    if (tid < nb) bsum[tid] = sm[tid] - v;   // inclusive -> exclusive
}

__global__ __launch_bounds__(256) void k_scan_final(
    const int* __restrict__ cnt, const int* __restrict__ bsum,
    int* __restrict__ rowp, int M, int total) {
    __shared__ int sm[256];
    int tid = threadIdx.x;
    int i = blockIdx.x * 256 + tid;
    int v = (i < M) ? cnt[i] : 0;
    sm[tid] = v;
    __syncthreads();
    for (int off = 1; off < 256; off <<= 1) {
        int u = (tid >= off) ? sm[tid - off] : 0;
        __syncthreads();
        sm[tid] += u;
        __syncthreads();
    }
    if (i < M) rowp[i] = bsum[blockIdx.x] + sm[tid] - v;
    if (i == 0) rowp[M] = total;
}

// scatter triplets into segment order; store cos(angle) (Chebyshev arg) and
// the edge id per position; permute t_src.
__global__ void k_scatter(const int* __restrict__ ts, const int* __restrict__ td,
                          const int* __restrict__ rowp, int* __restrict__ cursor,
                          const float* __restrict__ rn,
                          int* __restrict__ srcs, float* __restrict__ cosv,
                          int* __restrict__ eids, int T) {
    int t = blockIdx.x * blockDim.x + threadIdx.x;
    if (t >= T) return;
    int a = ts[t], b = td[t];
    float d = rn[a * 3 + 0] * rn[b * 3 + 0]
            + rn[a * 3 + 1] * rn[b * 3 + 1]
            + rn[a * 3 + 2] * rn[b * 3 + 2];
    d = fminf(1.0f, fmaxf(-1.0f, d));
    int pos = rowp[b] + atomicAdd(&cursor[b], 1);
    srcs[pos] = a;
    cosv[pos] = d;
    eids[pos] = b;
}

// scatter edge ids into node order (CSR by gd)
__global__ void k_escatter(const int* __restrict__ gd, const int* __restrict__ erowp,
                           int* __restrict__ cursor, int* __restrict__ eord, int E) {
    int e = blockIdx.x * blockDim.x + threadIdx.x;
    if (e >= E) return;
    int n = gd[e];
    int pos = erowp[n] + atomicAdd(&cursor[n], 1);
    eord[pos] = e;
}

// xs = x@Wsrc + bsrc ; xd = x@Wdst + bdst   (wave per node, lane = dm)
__global__ __launch_bounds__(256) void k_node_proj(
    const float* __restrict__ x,
    const float* __restrict__ Ws, const float* __restrict__ bs,
    const float* __restrict__ Wd, const float* __restrict__ bd,
    float* __restrict__ xs, float* __restrict__ xd, int N) {
    int lane = threadIdx.x & 63;
    int n = blockIdx.x * 4 + (threadIdx.x >> 6);
    if (n >= N) return;
    const float* xr = x + (size_t)n * DMODEL;
    float as = 0.f, ad = 0.f;
    for (int d = 0; d < DMODEL; ++d) {
        float xv = xr[d];
        as = fmaf(xv, Ws[d * DM + lane], as);
        ad = fmaf(xv, Wd[d * DM + lane], ad);
    }
    xs[n * DM + lane] = as + bs[lane];
    xd[n * DM + lane] = ad + bd[lane];
}

// xij[e][m] = RBF(bl[e]) @ Wedge + bedge + xs[g_src[e]] + xd[g_dst[e]]
// 64-edge x 64-col tile, k-major LDS, 4x4 register blocking, float4 reads.
__global__ __launch_bounds__(256) void k_xij(
    const float* __restrict__ bl,
    const float* __restrict__ We, const float* __restrict__ be,
    const float* __restrict__ xs, const float* __restrict__ xd,
    const int* __restrict__ gs, const int* __restrict__ gd,
    float* __restrict__ xij, int E) {
    __shared__ float A[32][68];   // A[kk][edge]
    __shared__ float B[32][68];   // B[kk][col]
    int tid = threadIdx.x;
    int e0 = blockIdx.x * 64;
    int ty = tid >> 4, tx = tid & 15;
    int row = tid & 63;           // edge row this thread stages
    int kbase = tid >> 6;         // 0..3
    const float step = 8.0f / 255.0f;
    const float gamma = (255.0f / 8.0f) * (255.0f / 8.0f);
    int erow = e0 + row;
    float blv = (erow < E) ? bl[erow] : 0.f;
    float acc[4][4] = {};
    for (int k0 = 0; k0 < DMODEL; k0 += 32) {
        #pragma unroll
        for (int i = 0; i < 8; ++i) {
            int kk = i * 4 + kbase;
            float c = (float)(k0 + kk) * step;
            float dd = blv - c;
            A[kk][row] = __expf(-gamma * dd * dd);
            B[kk][row] = We[(size_t)(k0 + kk) * DM + row];
        }
        __syncthreads();
        for (int kk = 0; kk < 32; ++kk) {
            float4 av = *(const float4*)&A[kk][ty * 4];
            float4 bv = *(const float4*)&B[kk][tx * 4];
            float a4[4] = {av.x, av.y, av.z, av.w};
            float b4[4] = {bv.x, bv.y, bv.z, bv.w};
            for (int i = 0; i < 4; ++i)
                for (int j = 0; j < 4; ++j)
                    acc[i][j] = fmaf(a4[i], b4[j], acc[i][j]);
        }
        __syncthreads();
    }
    int m0 = tx * 4;
    float4 bev = *(const float4*)&be[m0];
    for (int i = 0; i < 4; ++i) {
        int e = e0 + ty * 4 + i;
        if (e >= E) continue;
        int s = gs[e], d2 = gd[e];
        float4 xsv = *(const float4*)&xs[(size_t)s * DM + m0];
        float4 xdv = *(const float4*)&xd[(size_t)d2 * DM + m0];
        float4 o;
        o.x = acc[i][0] + xsv.x + xdv.x + bev.x;
        o.y = acc[i][1] + xsv.y + xdv.y + bev.y;
        o.z = acc[i][2] + xsv.z + xdv.z + bev.z;
        o.w = acc[i][3] + xsv.w + xdv.w + bev.w;
        *(float4*)&xij[(size_t)e * DM + m0] = o;
    }
}

// thread per triplet: logit[p] = sum_k silu(T_k(cos) + xs_row[k] + xe_row[k]) * attn[k]
// Chebyshev recurrence T_k = 2c*T_{k-1} - T_{k-2}; float4 row loads; no
// cross-lane ops at all.
__global__ __launch_bounds__(256) void k_logit(
    const float* __restrict__ xij, const float* __restrict__ cosv,
    const int* __restrict__ srcs, const int* __restrict__ eids,
    const float* __restrict__ attn_l, float* __restrict__ logits, int T) {
    int p = blockIdx.x * 256 + threadIdx.x;
    if (p >= T) return;
    int s = srcs[p], e = eids[p];
    float c = cosv[p];
    float c2 = 2.0f * c;
    const float4* xsr = (const float4*)(xij + (size_t)s * DM);
    const float4* xer = (const float4*)(xij + (size_t)e * DM);
    float t0 = 1.0f, t1 = c;
    float acc = 0.f;
    #pragma unroll
    for (int j = 0; j < 16; ++j) {
        float4 a4 = xsr[j];
        float4 b4 = xer[j];
        float u[4] = {a4.x + b4.x, a4.y + b4.y, a4.z + b4.z, a4.w + b4.w};
        #pragma unroll
        for (int q = 0; q < 4; ++q) {
            int k = j * 4 + q;
            float tk;
            if (k == 0)      tk = 1.0f;
            else if (k == 1) tk = c;
            else { tk = fmaf(c2, t1, -t0); t0 = t1; t1 = tk; }
            float v = tk + u[q];
            float sl = v / (1.0f + __expf(-v));
            acc = fmaf(sl, attn_l[k], acc);
        }
    }
    logits[p] = acc;
}

// thread per (edge, channel-quad): softmax over segment logits + weighted
// float4 gather of source rows. Plain stores to msg (no atomics).
__global__ __launch_bounds__(256) void k_attend(
    const float* __restrict__ xij, const float* __restrict__ logits,
    const int* __restrict__ srcs, const int* __restrict__ rowp,
    float* __restrict__ msg, int E) {
    int gtid = blockIdx.x * 256 + threadIdx.x;
    int e = gtid >> 4;
    if (e >= E) return;
    int quad = gtid & 15;
    int beg = rowp[e], end = rowp[e + 1];
    float4 acc = {0.f, 0.f, 0.f, 0.f};
    if (beg < end) {
        float lm = -1e30f;
        for (int p = beg; p < end; ++p) lm = fmaxf(lm, logits[p]);
        float den = 0.f;
        for (int p = beg; p < end; ++p) {
            float w = __expf(logits[p] - lm);
            den += w;
            float4 v = *(const float4*)&xij[(size_t)srcs[p] * DM + quad * 4];
            acc.x = fmaf(w, v.x, acc.x);
            acc.y = fmaf(w, v.y, acc.y);
            acc.z = fmaf(w, v.z, acc.z);
            acc.w = fmaf(w, v.w, acc.w);
        }
        float inv = 1.0f / den;
        acc.x *= inv; acc.y *= inv; acc.z *= inv; acc.w *= inv;
    }
    *(float4*)&msg[(size_t)e * DM + quad * 4] = acc;
}

// thread per (node, channel-quad): sum msg over this node's incoming edges.
__global__ __launch_bounds__(256) void k_aggregate(
    const float* __restrict__ msg, const int* __restrict__ erowp,
    const int* __restrict__ eord, float* __restrict__ ft, int N) {
    int gtid = blockIdx.x * 256 + threadIdx.x;
    int n = gtid >> 4;
    if (n >= N) return;
    int quad = gtid & 15;
    int beg = erowp[n], end = erowp[n + 1];
    float4 acc = {0.f, 0.f, 0.f, 0.f};
    for (int j = beg; j < end; ++j) {
        float4 v = *(const float4*)&msg[(size_t)eord[j] * DM + quad * 4];
        acc.x += v.x; acc.y += v.y; acc.z += v.z; acc.w += v.w;
    }
    *(float4*)&ft[(size_t)n * DM + quad * 4] = acc;
}

// h = silu(ft @ W1 + b1): 64-node x 64-hcol tile, 4x4 register blocking.
// grid (ceil(N/64), HDIM/64) = (157, 16)
__global__ __launch_bounds__(256) void k_ffn1(
    const float* __restrict__ ft, const float* __restrict__ W1,
    const float* __restrict__ b1, float* __restrict__ h, int N) {
    __shared__ float A[32][68];   // A[kk][node], k-major, +4 pad (16B-aligned rows)
    __shared__ float B[32][68];   // B[kk][col]
    int tid = threadIdx.x;
    int n0 = blockIdx.x * 64;
    int c0 = blockIdx.y * 64;
    int ty = tid >> 4, tx = tid & 15;
    float acc[4][4] = {};
    for (int k0 = 0; k0 < DM; k0 += 32) {
        for (int i = 0; i < 8; ++i) {
            int flat = i * 256 + tid;
            int row = flat >> 5, kk = flat & 31;
            int n = n0 + row;
            A[kk][row] = (n < N) ? ft[(size_t)n * DM + k0 + kk] : 0.f;
        }
        for (int i = 0; i < 8; ++i) {
            int flat = i * 256 + tid;
            int kk = flat >> 6, col = flat & 63;
            B[kk][col] = W1[(size_t)(k0 + kk) * HDIM + c0 + col];
        }
        __syncthreads();
        for (int kk = 0; kk < 32; ++kk) {
            float4 av = *(const float4*)&A[kk][ty * 4];
            float4 bv = *(const float4*)&B[kk][tx * 4];
            float a4[4] = {av.x, av.y, av.z, av.w};
            float b4[4] = {bv.x, bv.y, bv.z, bv.w};
            for (int i = 0; i < 4; ++i)
                for (int j = 0; j < 4; ++j)
                    acc[i][j] = fmaf(a4[i], b4[j], acc[i][j]);
        }
        __syncthreads();
    }
    float4 bb = *(const float4*)&b1[c0 + tx * 4];
    float b4[4] = {bb.x, bb.y, bb.z, bb.w};
    for (int i = 0; i < 4; ++i) {
        int n = n0 + ty * 4 + i;
        if (n >= N) continue;
        float4 o;
        float v0 = acc[i][0] + b4[0], v1 = acc[i][1] + b4[1];
        float v2 = acc[i][2] + b4[2], v3 = acc[i][3] + b4[3];
        o.x = v0 / (1.0f + __expf(-v0));
        o.y = v1 / (1.0f + __expf(-v1));
        o.z = v2 / (1.0f + __expf(-v2));
        o.w = v3 / (1.0f + __expf(-v3));
        *(float4*)&h[(size_t)n * HDIM + c0 + tx * 4] = o;
    }
}

// x = h @ W2 + b2: 64-node x 64-col tile, 4x4 register blocking.
// grid (ceil(N/64), DMODEL/64) = (157, 4)
__global__ __launch_bounds__(256) void k_ffn2(
    const float* __restrict__ h, const float* __restrict__ W2,
    const float* __restrict__ b2, float* __restrict__ x, int N) {
    __shared__ float A[32][68];
    __shared__ float B[32][68];
    int tid = threadIdx.x;
    int n0 = blockIdx.x * 64;
    int c0 = blockIdx.y * 64;
    int ty = tid >> 4, tx = tid & 15;
    float acc[4][4] = {};
    for (int k0 = 0; k0 < HDIM; k0 += 32) {
        for (int i = 0; i < 8; ++i) {
            int flat = i * 256 + tid;
            int row = flat >> 5, kk = flat & 31;
            int n = n0 + row;
            A[kk][row] = (n < N) ? h[(size_t)n * HDIM + k0 + kk] : 0.f;
        }
        for (int i = 0; i < 8; ++i) {
            int flat = i * 256 + tid;
            int kk = flat >> 6, col = flat & 63;
            B[kk][col] = W2[(size_t)(k0 + kk) * DMODEL + c0 + col];
        }
        __syncthreads();
        for (int kk = 0; kk < 32; ++kk) {
            float4 av = *(const float4*)&A[kk][ty * 4];
            float4 bv = *(const float4*)&B[kk][tx * 4];
            float a4[4] = {av.x, av.y, av.z, av.w};
            float b4[4] = {bv.x, bv.y, bv.z, bv.w};
            for (int i = 0; i < 4; ++i)
                for (int j = 0; j < 4; ++j)
                    acc[i][j] = fmaf(a4[i], b4[j], acc[i][j]);
        }
        __syncthreads();
    }
    float4 bb = *(const float4*)&b2[c0 + tx * 4];
    float b4[4] = {bb.x, bb.y, bb.z, bb.w};
    for (int i = 0; i < 4; ++i) {
        int n = n0 + ty * 4 + i;
        if (n >= N) continue;
        float4 o;
        o.x = acc[i][0] + b4[0];
        o.y = acc[i][1] + b4[1];
        o.z = acc[i][2] + b4[2];
        o.w = acc[i][3] + b4[3];
        *(float4*)&x[(size_t)n * DMODEL + c0 + tx * 4] = o;
    }
}

// grid-stride dot(x, tiled Wfc) with per-block LDS reduction -> 1 atomic/block.
__global__ __launch_bounds__(256) void k_out_reduce(
    const float* __restrict__ x, const float* __restrict__ Wfc,
    float* __restrict__ acc, int NT) {
    __shared__ float sm[4];
    int tid = threadIdx.x;
    float v = 0.f;
    for (int i = blockIdx.x * blockDim.x + tid; i < NT; i += gridDim.x * blockDim.x)
        v = fmaf(x[i], Wfc[i & (DMODEL - 1)], v);
    for (int off = 32; off > 0; off >>= 1) v += __shfl_xor(v, off, 64);
    if ((tid & 63) == 0) sm[tid >> 6] = v;
    __syncthreads();
    if (tid == 0) {
        float s = sm[0] + sm[1] + sm[2] + sm[3];
        atomicAdd(acc, s);
    }
}

__global__ void k_out_final(const float* __restrict__ acc, const float* __restrict__ bfc,
                            float* __restrict__ out, float invN) {
    out[0] = acc[0] * invN + bfc[0];
}

extern "C" void kernel_launch(void* const* d_in, const int* in_sizes, int n_in,
                              void* d_out, int out_size, void* d_ws, size_t ws_size,
                              hipStream_t stream) {
    const int*   an    = (const int*)d_in[0];
    const int*   gs    = (const int*)d_in[1];
    const int*   gd    = (const int*)d_in[2];
    const int*   ts    = (const int*)d_in[3];
    const int*   td    = (const int*)d_in[4];
    const float* r     = (const float*)d_in[5];
    const float* emb   = (const float*)d_in[6];
    const float* Wsrc  = (const float*)d_in[7];
    const float* bsrc  = (const float*)d_in[8];
    const float* Wdst  = (const float*)d_in[9];
    const float* bdst  = (const float*)d_in[10];
    const float* Wedge = (const float*)d_in[11];
    const float* bedge = (const float*)d_in[12];
    const float* attn  = (const float*)d_in[13];
    const float* W1    = (const float*)d_in[14];
    const float* b1    = (const float*)d_in[15];
    const float* W2    = (const float*)d_in[16];
    const float* b2    = (const float*)d_in[17];
    const float* Wfc   = (const float*)d_in[18];
    const float* bfc   = (const float*)d_in[19];

    const int N = in_sizes[0];
    const int E = in_sizes[1];
    const int T = in_sizes[3];

    char* w = (char*)d_ws;
    size_t off = 0;
    auto alloc = [&](size_t elems) {
        void* p = w + off;
        off += ((elems * 4 + 255) / 256) * 256;
        return p;
    };
    float* x      = (float*)alloc((size_t)N * DMODEL);
    float* rn     = (float*)alloc((size_t)E * 3);
    float* bl     = (float*)alloc((size_t)E);
    int*   cnt    = (int*)  alloc((size_t)E);
    int*   rowp   = (int*)  alloc((size_t)E + 1);
    int*   bsum   = (int*)  alloc(1024);
    int*   srcs   = (int*)  alloc((size_t)T);
    float* cosv   = (float*)alloc((size_t)T);
    int*   eids   = (int*)  alloc((size_t)T);
    float* logits = (float*)alloc((size_t)T);
    int*   ecnt   = (int*)  alloc((size_t)N);
    int*   erowp  = (int*)  alloc((size_t)N + 1);
    int*   eord   = (int*)  alloc((size_t)E);
    float* xs     = (float*)alloc((size_t)N * DM);
    float* xd     = (float*)alloc((size_t)N * DM);
    float* xij    = (float*)alloc((size_t)E * DM);
    float* ft     = (float*)alloc((size_t)N * DM);
    float* h      = (float*)alloc((size_t)N * HDIM);
    float* accs   = (float*)alloc(16);
    float* msg    = h;   // aliased: msg (attend->aggregate) and h (ffn1->ffn2)
                         // have disjoint lifetimes; E*DM <= N*HDIM.
    (void)ws_size; (void)n_in; (void)out_size;

    const int nbScanE = (E + 255) / 256;   // 625 <= 1024
    const int nbScanN = (N + 255) / 256;   // 40   <= 1024

    // ---- setup (layer-invariant) ----
    k_embed<<<N, 256, 0, stream>>>(an, emb, x);
    k_edge_geom<<<(E + 255) / 256, 256, 0, stream>>>(r, bl, rn, E);
    // triplet CSR by t_dst
    hipMemsetAsync(cnt, 0, (size_t)E * 4, stream);
    k_hist<<<(T + 255) / 256, 256, 0, stream>>>(td, cnt, T);
    k_scan_part<<<nbScanE, 256, 0, stream>>>(cnt, bsum, E);
    k_scan_mid<<<1, 1024, 0, stream>>>(bsum, nbScanE);
    k_scan_final<<<nbScanE, 256, 0, stream>>>(cnt, bsum, rowp, E, T);
    hipMemsetAsync(cnt, 0, (size_t)E * 4, stream);
    k_scatter<<<(T + 255) / 256, 256, 0, stream>>>(ts, td, rowp, cnt, rn,
                                                   srcs, cosv, eids, T);
    // edge CSR by gd
    hipMemsetAsync(ecnt, 0, (size_t)N * 4, stream);
    k_hist<<<(E + 255) / 256, 256, 0, stream>>>(gd, ecnt, E);
    k_scan_part<<<nbScanN, 256, 0, stream>>>(ecnt, bsum, N);
    k_scan_mid<<<1, 1024, 0, stream>>>(bsum, nbScanN);
    k_scan_final<<<nbScanN, 256, 0, stream>>>(ecnt, bsum, erowp, N, E);
    hipMemsetAsync(ecnt, 0, (size_t)N * 4, stream);
    k_escatter<<<(E + 255) / 256, 256, 0, stream>>>(gd, erowp, ecnt, eord, E);

    // ---- layers ----
    for (int l = 0; l < 3; ++l) {
        k_node_proj<<<(N + 3) / 4, 256, 0, stream>>>(
            x, Wsrc + l * DMODEL * DM, bsrc + l * DM,
            Wdst + l * DMODEL * DM, bdst + l * DM, xs, xd, N);
        k_xij<<<(E + 63) / 64, 256, 0, stream>>>(
            bl, Wedge + l * DMODEL * DM, bedge + l * DM, xs, xd, gs, gd, xij, E);
        k_logit<<<(T + 255) / 256, 256, 0, stream>>>(
            xij, cosv, srcs, eids, attn + l * DM, logits, T);
        k_attend<<<(E * 16 + 255) / 256, 256, 0, stream>>>(
            xij, logits, srcs, rowp, msg, E);
        k_aggregate<<<(N * 16 + 255) / 256, 256, 0, stream>>>(
            msg, erowp, eord, ft, N);
        k_ffn1<<<dim3((N + 63) / 64, HDIM / 64), 256, 0, stream>>>(
            ft, W1 + l * DM * HDIM, b1 + l * HDIM, h, N);
        k_ffn2<<<dim3((N + 63) / 64, DMODEL / 64), 256, 0, stream>>>(
            h, W2 + l * HDIM * DMODEL, b2 + l * DMODEL, x, N);
    }

    // ---- output head ----
    hipMemsetAsync(accs, 0, 4, stream);
    k_out_reduce<<<120, 256, 0, stream>>>(x, Wfc, accs, N * DMODEL);
    k_out_final<<<1, 1, 0, stream>>>(accs, bfc, (float*)d_out, 1.0f / (float)N);
}

// Round 7
// 1572.673 us; speedup vs baseline: 1.3618x; 1.0342x over previous
//
#include <hip/hip_runtime.h>
#include <math.h>

// M3GNet-like GNN forward. N=10000 nodes, E=160000 edges, T=1200000 triplets,
// D=256, DM=64, H=1024, L=3, output = scalar mean energy (fp32).
//
// R6: split-K k_ffn2. R5's ffn2 was dispatch-limited: 628 blocks = 2.45/CU
// (occupancy 25%), so 32 k-iters x 2 barriers had nothing to overlap with.
// Now grid (157,4,4): 2512 blocks, K=256 chunk each, partials into the dead
// xij buffer (4*N*256 == E*64 exactly), reduced by k_ffn2_reduce (+bias).

#define DM 64
#define DMODEL 256
#define HDIM 1024

__global__ void k_embed(const int* __restrict__ an, const float* __restrict__ emb,
                        float* __restrict__ x) {
    int n = blockIdx.x;
    int d = threadIdx.x;          // blockDim = 256
    x[n * DMODEL + d] = emb[an[n] * DMODEL + d];
}

__global__ void k_edge_geom(const float* __restrict__ r, float* __restrict__ bl,
                            float* __restrict__ rn, int E) {
    int e = blockIdx.x * blockDim.x + threadIdx.x;
    if (e >= E) return;
    float a = r[e * 3 + 0], b = r[e * 3 + 1], c = r[e * 3 + 2];
    float l = sqrtf(a * a + b * b + c * c);
    bl[e] = l;
    float inv = 1.0f / l;
    // note: reference uses -r/|r| for both operands of the dot; signs cancel.
    rn[e * 3 + 0] = a * inv;
    rn[e * 3 + 1] = b * inv;
    rn[e * 3 + 2] = c * inv;
}

__global__ void k_hist(const int* __restrict__ idx, int* __restrict__ cnt, int M) {
    int t = blockIdx.x * blockDim.x + threadIdx.x;
    if (t < M) atomicAdd(&cnt[idx[t]], 1);
}

// ---- 3-phase exclusive scan of cnt[M] -> rowp[M+1] (generic) ----
__global__ __launch_bounds__(256) void k_scan_part(
    const int* __restrict__ cnt, int* __restrict__ bsum, int M) {
    __shared__ int sm[4];
    int tid = threadIdx.x;
    int i = blockIdx.x * 256 + tid;
    int v = (i < M) ? cnt[i] : 0;
    for (int off = 32; off > 0; off >>= 1) v += __shfl_xor(v, off, 64);
    if ((tid & 63) == 0) sm[tid >> 6] = v;
    __syncthreads();
    if (tid == 0) bsum[blockIdx.x] = sm[0] + sm[1] + sm[2] + sm[3];
}

__global__ __launch_bounds__(1024) void k_scan_mid(int* __restrict__ bsum, int nb) {
    __shared__ int sm[1024];
    int tid = threadIdx.x;
    int v = (tid < nb) ? bsum[tid] : 0;
    sm[tid] = v;
    __syncthreads();
    for (int off = 1; off < 1024; off <<= 1) {
        int u = (tid >= off) ? sm[tid - off] : 0;
        __syncthreads();
        sm[tid] += u;
        __syncthreads();
    }
    if (tid < nb) bsum[tid] = sm[tid] - v;   // inclusive -> exclusive
}

__global__ __launch_bounds__(256) void k_scan_final(
    const int* __restrict__ cnt, const int* __restrict__ bsum,
    int* __restrict__ rowp, int M, int total) {
    __shared__ int sm[256];
    int tid = threadIdx.x;
    int i = blockIdx.x * 256 + tid;
    int v = (i < M) ? cnt[i] : 0;
    sm[tid] = v;
    __syncthreads();
    for (int off = 1; off < 256; off <<= 1) {
        int u = (tid >= off) ? sm[tid - off] : 0;
        __syncthreads();
        sm[tid] += u;
        __syncthreads();
    }
    if (i < M) rowp[i] = bsum[blockIdx.x] + sm[tid] - v;
    if (i == 0) rowp[M] = total;
}

// scatter triplets into segment order; store cos(angle) (Chebyshev arg) and
// the edge id per position; permute t_src.
__global__ void k_scatter(const int* __restrict__ ts, const int* __restrict__ td,
                          const int* __restrict__ rowp, int* __restrict__ cursor,
                          const float* __restrict__ rn,
                          int* __restrict__ srcs, float* __restrict__ cosv,
                          int* __restrict__ eids, int T) {
    int t = blockIdx.x * blockDim.x + threadIdx.x;
    if (t >= T) return;
    int a = ts[t], b = td[t];
    float d = rn[a * 3 + 0] * rn[b * 3 + 0]
            + rn[a * 3 + 1] * rn[b * 3 + 1]
            + rn[a * 3 + 2] * rn[b * 3 + 2];
    d = fminf(1.0f, fmaxf(-1.0f, d));
    int pos = rowp[b] + atomicAdd(&cursor[b], 1);
    srcs[pos] = a;
    cosv[pos] = d;
    eids[pos] = b;
}

// scatter edge ids into node order (CSR by gd)
__global__ void k_escatter(const int* __restrict__ gd, const int* __restrict__ erowp,
                           int* __restrict__ cursor, int* __restrict__ eord, int E) {
    int e = blockIdx.x * blockDim.x + threadIdx.x;
    if (e >= E) return;
    int n = gd[e];
    int pos = erowp[n] + atomicAdd(&cursor[n], 1);
    eord[pos] = e;
}

// xs = x@Wsrc + bsrc ; xd = x@Wdst + bdst   (wave per node, lane = dm)
__global__ __launch_bounds__(256) void k_node_proj(
    const float* __restrict__ x,
    const float* __restrict__ Ws, const float* __restrict__ bs,
    const float* __restrict__ Wd, const float* __restrict__ bd,
    float* __restrict__ xs, float* __restrict__ xd, int N) {
    int lane = threadIdx.x & 63;
    int n = blockIdx.x * 4 + (threadIdx.x >> 6);
    if (n >= N) return;
    const float* xr = x + (size_t)n * DMODEL;
    float as = 0.f, ad = 0.f;
    for (int d = 0; d < DMODEL; ++d) {
        float xv = xr[d];
        as = fmaf(xv, Ws[d * DM + lane], as);
        ad = fmaf(xv, Wd[d * DM + lane], ad);
    }
    xs[n * DM + lane] = as + bs[lane];
    xd[n * DM + lane] = ad + bd[lane];
}

// xij[e][m] = RBF(bl[e]) @ Wedge + bedge + xs[g_src[e]] + xd[g_dst[e]]
// 64-edge x 64-col tile, k-major LDS, 4x4 register blocking, float4 reads.
__global__ __launch_bounds__(256) void k_xij(
    const float* __restrict__ bl,
    const float* __restrict__ We, const float* __restrict__ be,
    const float* __restrict__ xs, const float* __restrict__ xd,
    const int* __restrict__ gs, const int* __restrict__ gd,
    float* __restrict__ xij, int E) {
    __shared__ float A[32][68];   // A[kk][edge]
    __shared__ float B[32][68];   // B[kk][col]
    int tid = threadIdx.x;
    int e0 = blockIdx.x * 64;
    int ty = tid >> 4, tx = tid & 15;
    int row = tid & 63;           // edge row this thread stages
    int kbase = tid >> 6;         // 0..3
    const float step = 8.0f / 255.0f;
    const float gamma = (255.0f / 8.0f) * (255.0f / 8.0f);
    int erow = e0 + row;
    float blv = (erow < E) ? bl[erow] : 0.f;
    float acc[4][4] = {};
    for (int k0 = 0; k0 < DMODEL; k0 += 32) {
        #pragma unroll
        for (int i = 0; i < 8; ++i) {
            int kk = i * 4 + kbase;
            float c = (float)(k0 + kk) * step;
            float dd = blv - c;
            A[kk][row] = __expf(-gamma * dd * dd);
            B[kk][row] = We[(size_t)(k0 + kk) * DM + row];
        }
        __syncthreads();
        for (int kk = 0; kk < 32; ++kk) {
            float4 av = *(const float4*)&A[kk][ty * 4];
            float4 bv = *(const float4*)&B[kk][tx * 4];
            float a4[4] = {av.x, av.y, av.z, av.w};
            float b4[4] = {bv.x, bv.y, bv.z, bv.w};
            for (int i = 0; i < 4; ++i)
                for (int j = 0; j < 4; ++j)
                    acc[i][j] = fmaf(a4[i], b4[j], acc[i][j]);
        }
        __syncthreads();
    }
    int m0 = tx * 4;
    float4 bev = *(const float4*)&be[m0];
    for (int i = 0; i < 4; ++i) {
        int e = e0 + ty * 4 + i;
        if (e >= E) continue;
        int s = gs[e], d2 = gd[e];
        float4 xsv = *(const float4*)&xs[(size_t)s * DM + m0];
        float4 xdv = *(const float4*)&xd[(size_t)d2 * DM + m0];
        float4 o;
        o.x = acc[i][0] + xsv.x + xdv.x + bev.x;
        o.y = acc[i][1] + xsv.y + xdv.y + bev.y;
        o.z = acc[i][2] + xsv.z + xdv.z + bev.z;
        o.w = acc[i][3] + xsv.w + xdv.w + bev.w;
        *(float4*)&xij[(size_t)e * DM + m0] = o;
    }
}

// thread per triplet: logit[p] = sum_k silu(T_k(cos) + xs_row[k] + xe_row[k]) * attn[k]
// Chebyshev recurrence T_k = 2c*T_{k-1} - T_{k-2}; float4 row loads; no
// cross-lane ops at all.
__global__ __launch_bounds__(256) void k_logit(
    const float* __restrict__ xij, const float* __restrict__ cosv,
    const int* __restrict__ srcs, const int* __restrict__ eids,
    const float* __restrict__ attn_l, float* __restrict__ logits, int T) {
    int p = blockIdx.x * 256 + threadIdx.x;
    if (p >= T) return;
    int s = srcs[p], e = eids[p];
    float c = cosv[p];
    float c2 = 2.0f * c;
    const float4* xsr = (const float4*)(xij + (size_t)s * DM);
    const float4* xer = (const float4*)(xij + (size_t)e * DM);
    float t0 = 1.0f, t1 = c;
    float acc = 0.f;
    #pragma unroll
    for (int j = 0; j < 16; ++j) {
        float4 a4 = xsr[j];
        float4 b4 = xer[j];
        float u[4] = {a4.x + b4.x, a4.y + b4.y, a4.z + b4.z, a4.w + b4.w};
        #pragma unroll
        for (int q = 0; q < 4; ++q) {
            int k = j * 4 + q;
            float tk;
            if (k == 0)      tk = 1.0f;
            else if (k == 1) tk = c;
            else { tk = fmaf(c2, t1, -t0); t0 = t1; t1 = tk; }
            float v = tk + u[q];
            float sl = v / (1.0f + __expf(-v));
            acc = fmaf(sl, attn_l[k], acc);
        }
    }
    logits[p] = acc;
}

// thread per (edge, channel-quad): softmax over segment logits + weighted
// float4 gather of source rows. Plain stores to msg (no atomics).
__global__ __launch_bounds__(256) void k_attend(
    const float* __restrict__ xij, const float* __restrict__ logits,
    const int* __restrict__ srcs, const int* __restrict__ rowp,
    float* __restrict__ msg, int E) {
    int gtid = blockIdx.x * 256 + threadIdx.x;
    int e = gtid >> 4;
    if (e >= E) return;
    int quad = gtid & 15;
    int beg = rowp[e], end = rowp[e + 1];
    float4 acc = {0.f, 0.f, 0.f, 0.f};
    if (beg < end) {
        float lm = -1e30f;
        for (int p = beg; p < end; ++p) lm = fmaxf(lm, logits[p]);
        float den = 0.f;
        for (int p = beg; p < end; ++p) {
            float w = __expf(logits[p] - lm);
            den += w;
            float4 v = *(const float4*)&xij[(size_t)srcs[p] * DM + quad * 4];
            acc.x = fmaf(w, v.x, acc.x);
            acc.y = fmaf(w, v.y, acc.y);
            acc.z = fmaf(w, v.z, acc.z);
            acc.w = fmaf(w, v.w, acc.w);
        }
        float inv = 1.0f / den;
        acc.x *= inv; acc.y *= inv; acc.z *= inv; acc.w *= inv;
    }
    *(float4*)&msg[(size_t)e * DM + quad * 4] = acc;
}

// thread per (node, channel-quad): sum msg over this node's incoming edges.
__global__ __launch_bounds__(256) void k_aggregate(
    const float* __restrict__ msg, const int* __restrict__ erowp,
    const int* __restrict__ eord, float* __restrict__ ft, int N) {
    int gtid = blockIdx.x * 256 + threadIdx.x;
    int n = gtid >> 4;
    if (n >= N) return;
    int quad = gtid & 15;
    int beg = erowp[n], end = erowp[n + 1];
    float4 acc = {0.f, 0.f, 0.f, 0.f};
    for (int j = beg; j < end; ++j) {
        float4 v = *(const float4*)&msg[(size_t)eord[j] * DM + quad * 4];
        acc.x += v.x; acc.y += v.y; acc.z += v.z; acc.w += v.w;
    }
    *(float4*)&ft[(size_t)n * DM + quad * 4] = acc;
}

// h = silu(ft @ W1 + b1): 64-node x 64-hcol tile, 4x4 register blocking.
// grid (ceil(N/64), HDIM/64) = (157, 16)
__global__ __launch_bounds__(256) void k_ffn1(
    const float* __restrict__ ft, const float* __restrict__ W1,
    const float* __restrict__ b1, float* __restrict__ h, int N) {
    __shared__ float A[32][68];   // A[kk][node], k-major, +4 pad (16B-aligned rows)
    __shared__ float B[32][68];   // B[kk][col]
    int tid = threadIdx.x;
    int n0 = blockIdx.x * 64;
    int c0 = blockIdx.y * 64;
    int ty = tid >> 4, tx = tid & 15;
    float acc[4][4] = {};
    for (int k0 = 0; k0 < DM; k0 += 32) {
        for (int i = 0; i < 8; ++i) {
            int flat = i * 256 + tid;
            int row = flat >> 5, kk = flat & 31;
            int n = n0 + row;
            A[kk][row] = (n < N) ? ft[(size_t)n * DM + k0 + kk] : 0.f;
        }
        for (int i = 0; i < 8; ++i) {
            int flat = i * 256 + tid;
            int kk = flat >> 6, col = flat & 63;
            B[kk][col] = W1[(size_t)(k0 + kk) * HDIM + c0 + col];
        }
        __syncthreads();
        for (int kk = 0; kk < 32; ++kk) {
            float4 av = *(const float4*)&A[kk][ty * 4];
            float4 bv = *(const float4*)&B[kk][tx * 4];
            float a4[4] = {av.x, av.y, av.z, av.w};
            float b4[4] = {bv.x, bv.y, bv.z, bv.w};
            for (int i = 0; i < 4; ++i)
                for (int j = 0; j < 4; ++j)
                    acc[i][j] = fmaf(a4[i], b4[j], acc[i][j]);
        }
        __syncthreads();
    }
    float4 bb = *(const float4*)&b1[c0 + tx * 4];
    float b4[4] = {bb.x, bb.y, bb.z, bb.w};
    for (int i = 0; i < 4; ++i) {
        int n = n0 + ty * 4 + i;
        if (n >= N) continue;
        float4 o;
        float v0 = acc[i][0] + b4[0], v1 = acc[i][1] + b4[1];
        float v2 = acc[i][2] + b4[2], v3 = acc[i][3] + b4[3];
        o.x = v0 / (1.0f + __expf(-v0));
        o.y = v1 / (1.0f + __expf(-v1));
        o.z = v2 / (1.0f + __expf(-v2));
        o.w = v3 / (1.0f + __expf(-v3));
        *(float4*)&h[(size_t)n * HDIM + c0 + tx * 4] = o;
    }
}

// split-K ffn2: xpart[kq][n][c] = h[:, kq*256:(kq+1)*256] @ W2[chunk]
// grid (ceil(N/64), DMODEL/64, 4); 2512 blocks (~9/CU).
__global__ __launch_bounds__(256) void k_ffn2s(
    const float* __restrict__ h, const float* __restrict__ W2,
    float* __restrict__ xpart, int N) {
    __shared__ float A[32][68];
    __shared__ float B[32][68];
    int tid = threadIdx.x;
    int n0 = blockIdx.x * 64;
    int c0 = blockIdx.y * 64;
    int kq = blockIdx.z;
    int kstart = kq * (HDIM / 4);
    float* xp = xpart + (size_t)kq * N * DMODEL;
    int ty = tid >> 4, tx = tid & 15;
    float acc[4][4] = {};
    for (int k0 = kstart; k0 < kstart + HDIM / 4; k0 += 32) {
        for (int i = 0; i < 8; ++i) {
            int flat = i * 256 + tid;
            int row = flat >> 5, kk = flat & 31;
            int n = n0 + row;
            A[kk][row] = (n < N) ? h[(size_t)n * HDIM + k0 + kk] : 0.f;
        }
        for (int i = 0; i < 8; ++i) {
            int flat = i * 256 + tid;
            int kk = flat >> 6, col = flat & 63;
            B[kk][col] = W2[(size_t)(k0 + kk) * DMODEL + c0 + col];
        }
        __syncthreads();
        for (int kk = 0; kk < 32; ++kk) {
            float4 av = *(const float4*)&A[kk][ty * 4];
            float4 bv = *(const float4*)&B[kk][tx * 4];
            float a4[4] = {av.x, av.y, av.z, av.w};
            float b4[4] = {bv.x, bv.y, bv.z, bv.w};
            for (int i = 0; i < 4; ++i)
                for (int j = 0; j < 4; ++j)
                    acc[i][j] = fmaf(a4[i], b4[j], acc[i][j]);
        }
        __syncthreads();
    }
    for (int i = 0; i < 4; ++i) {
        int n = n0 + ty * 4 + i;
        if (n >= N) continue;
        float4 o = {acc[i][0], acc[i][1], acc[i][2], acc[i][3]};
        *(float4*)&xp[(size_t)n * DMODEL + c0 + tx * 4] = o;
    }
}

// x[n][c] = sum_kq xpart[kq][n][c] + b2[c]   (thread per float4)
__global__ __launch_bounds__(256) void k_ffn2_reduce(
    const float* __restrict__ xpart, const float* __restrict__ b2,
    float* __restrict__ x, int N) {
    int gtid = blockIdx.x * 256 + threadIdx.x;
    int nq = N * (DMODEL / 4);
    if (gtid >= nq) return;
    int c4 = gtid & (DMODEL / 4 - 1);
    size_t idx = (size_t)gtid * 4;
    size_t stride = (size_t)N * DMODEL;
    float4 a = *(const float4*)&xpart[idx];
    float4 b = *(const float4*)&xpart[idx + stride];
    float4 c = *(const float4*)&xpart[idx + 2 * stride];
    float4 d = *(const float4*)&xpart[idx + 3 * stride];
    float4 bb = *(const float4*)&b2[c4 * 4];
    float4 o;
    o.x = a.x + b.x + c.x + d.x + bb.x;
    o.y = a.y + b.y + c.y + d.y + bb.y;
    o.z = a.z + b.z + c.z + d.z + bb.z;
    o.w = a.w + b.w + c.w + d.w + bb.w;
    *(float4*)&x[idx] = o;
}

// grid-stride dot(x, tiled Wfc) with per-block LDS reduction -> 1 atomic/block.
__global__ __launch_bounds__(256) void k_out_reduce(
    const float* __restrict__ x, const float* __restrict__ Wfc,
    float* __restrict__ acc, int NT) {
    __shared__ float sm[4];
    int tid = threadIdx.x;
    float v = 0.f;
    for (int i = blockIdx.x * blockDim.x + tid; i < NT; i += gridDim.x * blockDim.x)
        v = fmaf(x[i], Wfc[i & (DMODEL - 1)], v);
    for (int off = 32; off > 0; off >>= 1) v += __shfl_xor(v, off, 64);
    if ((tid & 63) == 0) sm[tid >> 6] = v;
    __syncthreads();
    if (tid == 0) {
        float s = sm[0] + sm[1] + sm[2] + sm[3];
        atomicAdd(acc, s);
    }
}

__global__ void k_out_final(const float* __restrict__ acc, const float* __restrict__ bfc,
                            float* __restrict__ out, float invN) {
    out[0] = acc[0] * invN + bfc[0];
}

extern "C" void kernel_launch(void* const* d_in, const int* in_sizes, int n_in,
                              void* d_out, int out_size, void* d_ws, size_t ws_size,
                              hipStream_t stream) {
    const int*   an    = (const int*)d_in[0];
    const int*   gs    = (const int*)d_in[1];
    const int*   gd    = (const int*)d_in[2];
    const int*   ts    = (const int*)d_in[3];
    const int*   td    = (const int*)d_in[4];
    const float* r     = (const float*)d_in[5];
    const float* emb   = (const float*)d_in[6];
    const float* Wsrc  = (const float*)d_in[7];
    const float* bsrc  = (const float*)d_in[8];
    const float* Wdst  = (const float*)d_in[9];
    const float* bdst  = (const float*)d_in[10];
    const float* Wedge = (const float*)d_in[11];
    const float* bedge = (const float*)d_in[12];
    const float* attn  = (const float*)d_in[13];
    const float* W1    = (const float*)d_in[14];
    const float* b1    = (const float*)d_in[15];
    const float* W2    = (const float*)d_in[16];
    const float* b2    = (const float*)d_in[17];
    const float* Wfc   = (const float*)d_in[18];
    const float* bfc   = (const float*)d_in[19];

    const int N = in_sizes[0];
    const int E = in_sizes[1];
    const int T = in_sizes[3];

    char* w = (char*)d_ws;
    size_t off = 0;
    auto alloc = [&](size_t elems) {
        void* p = w + off;
        off += ((elems * 4 + 255) / 256) * 256;
        return p;
    };
    float* x      = (float*)alloc((size_t)N * DMODEL);
    float* rn     = (float*)alloc((size_t)E * 3);
    float* bl     = (float*)alloc((size_t)E);
    int*   cnt    = (int*)  alloc((size_t)E);
    int*   rowp   = (int*)  alloc((size_t)E + 1);
    int*   bsum   = (int*)  alloc(1024);
    int*   srcs   = (int*)  alloc((size_t)T);
    float* cosv   = (float*)alloc((size_t)T);
    int*   eids   = (int*)  alloc((size_t)T);
    float* logits = (float*)alloc((size_t)T);
    int*   ecnt   = (int*)  alloc((size_t)N);
    int*   erowp  = (int*)  alloc((size_t)N + 1);
    int*   eord   = (int*)  alloc((size_t)E);
    float* xs     = (float*)alloc((size_t)N * DM);
    float* xd     = (float*)alloc((size_t)N * DM);
    float* xij    = (float*)alloc((size_t)E * DM);
    float* ft     = (float*)alloc((size_t)N * DM);
    float* h      = (float*)alloc((size_t)N * HDIM);
    float* accs   = (float*)alloc(16);
    float* msg    = h;     // aliased: msg (attend->aggregate) dies before ffn1 writes h
    float* xpart  = xij;   // aliased: xij dead after k_attend; 4*N*DMODEL == E*DM
    (void)ws_size; (void)n_in; (void)out_size;

    const int nbScanE = (E + 255) / 256;   // 625 <= 1024
    const int nbScanN = (N + 255) / 256;   // 40   <= 1024

    // ---- setup (layer-invariant) ----
    k_embed<<<N, 256, 0, stream>>>(an, emb, x);
    k_edge_geom<<<(E + 255) / 256, 256, 0, stream>>>(r, bl, rn, E);
    // triplet CSR by t_dst
    hipMemsetAsync(cnt, 0, (size_t)E * 4, stream);
    k_hist<<<(T + 255) / 256, 256, 0, stream>>>(td, cnt, T);
    k_scan_part<<<nbScanE, 256, 0, stream>>>(cnt, bsum, E);
    k_scan_mid<<<1, 1024, 0, stream>>>(bsum, nbScanE);
    k_scan_final<<<nbScanE, 256, 0, stream>>>(cnt, bsum, rowp, E, T);
    hipMemsetAsync(cnt, 0, (size_t)E * 4, stream);
    k_scatter<<<(T + 255) / 256, 256, 0, stream>>>(ts, td, rowp, cnt, rn,
                                                   srcs, cosv, eids, T);
    // edge CSR by gd
    hipMemsetAsync(ecnt, 0, (size_t)N * 4, stream);
    k_hist<<<(E + 255) / 256, 256, 0, stream>>>(gd, ecnt, E);
    k_scan_part<<<nbScanN, 256, 0, stream>>>(ecnt, bsum, N);
    k_scan_mid<<<1, 1024, 0, stream>>>(bsum, nbScanN);
    k_scan_final<<<nbScanN, 256, 0, stream>>>(ecnt, bsum, erowp, N, E);
    hipMemsetAsync(ecnt, 0, (size_t)N * 4, stream);
    k_escatter<<<(E + 255) / 256, 256, 0, stream>>>(gd, erowp, ecnt, eord, E);

    // ---- layers ----
    for (int l = 0; l < 3; ++l) {
        k_node_proj<<<(N + 3) / 4, 256, 0, stream>>>(
            x, Wsrc + l * DMODEL * DM, bsrc + l * DM,
            Wdst + l * DMODEL * DM, bdst + l * DM, xs, xd, N);
        k_xij<<<(E + 63) / 64, 256, 0, stream>>>(
            bl, Wedge + l * DMODEL * DM, bedge + l * DM, xs, xd, gs, gd, xij, E);
        k_logit<<<(T + 255) / 256, 256, 0, stream>>>(
            xij, cosv, srcs, eids, attn + l * DM, logits, T);
        k_attend<<<(E * 16 + 255) / 256, 256, 0, stream>>>(
            xij, logits, srcs, rowp, msg, E);
        k_aggregate<<<(N * 16 + 255) / 256, 256, 0, stream>>>(
            msg, erowp, eord, ft, N);
        k_ffn1<<<dim3((N + 63) / 64, HDIM / 64), 256, 0, stream>>>(
            ft, W1 + l * DM * HDIM, b1 + l * HDIM, h, N);
        k_ffn2s<<<dim3((N + 63) / 64, DMODEL / 64, 4), 256, 0, stream>>>(
            h, W2 + l * HDIM * DMODEL, xpart, N);
        k_ffn2_reduce<<<(N * DMODEL / 4 + 255) / 256, 256, 0, stream>>>(
            xpart, b2 + l * DMODEL, x, N);
    }

    // ---- output head ----
    hipMemsetAsync(accs, 0, 4, stream);
    k_out_reduce<<<120, 256, 0, stream>>>(x, Wfc, accs, N * DMODEL);
    k_out_final<<<1, 1, 0, stream>>>(accs, bfc, (float*)d_out, 1.0f / (float)N);
}